// Round 13
// baseline (316.363 us; speedup 1.0000x reference)
//
#include <hip/hip_runtime.h>
#include <math.h>

#define NEG_SLOPE 0.2f
#define EPSV 1e-16f
#define NPART 16

typedef _Float16 half4 __attribute__((ext_vector_type(4)));
typedef _Float16 half8 __attribute__((ext_vector_type(8)));
typedef float floatx2 __attribute__((ext_vector_type(2)));

// ---------------- CSR build ----------------

// block scan over 1024-node chunks; deg computed inline from degp; bsum = raw chunk sum
__global__ void k_scan_blk(const int* __restrict__ degp, int N,
                           int* __restrict__ rowptr, int* __restrict__ bsum){
    int b = blockIdx.x, t = threadIdx.x;
    int base = b * 1024 + t * 4;
    int v[4];
    #pragma unroll
    for (int j = 0; j < 4; j++){
        int n = base + j, s = 0;
        if (n < N){
            #pragma unroll
            for (int p = 0; p < NPART; p++) s += degp[p * N + n];
        }
        v[j] = s;
    }
    int s = v[0] + v[1] + v[2] + v[3];
    int lane = t & 63, wid = t >> 6;
    int x = s;
    #pragma unroll
    for (int off = 1; off < 64; off <<= 1){
        int y = __shfl_up(x, off, 64);
        if (lane >= off) x += y;
    }
    __shared__ int ws[4];
    if (lane == 63) ws[wid] = x;
    __syncthreads();
    int woff = 0;
    for (int w = 0; w < wid; w++) woff += ws[w];
    int run = woff + x - s;
    #pragma unroll
    for (int j = 0; j < 4; j++){
        if (base + j < N) rowptr[base + j] = run;
        run += v[j];
    }
    if (t == 255) bsum[b] = woff + x;
}

// rowptr += prefix(bsum); poff[p][n] = rowptr[n] + prefix_p(degp[.][n])
__global__ void k_finalize(const int* __restrict__ bsum, const int* __restrict__ degp,
                           int N, int ET,
                           int* __restrict__ rowptr, int* __restrict__ poff){
    int b = blockIdx.x, t = threadIdx.x;
    int n = b * 256 + t;
    int chunk = (b * 256) >> 10;           // wave-uniform
    int off = 0;
    for (int c = 0; c < chunk; c++) off += bsum[c];
    if (n < N){
        int r = rowptr[n] + off;
        rowptr[n] = r;
        int run = r;
        #pragma unroll
        for (int p = 0; p < NPART; p++){
            poff[p * N + n] = run;
            run += degp[p * N + n];
        }
    }
    if (n == 0) rowptr[N] = ET;
}

// atomic-free scatter (src only; dst implicit via rowptr ranges); partition = (i>>8)&15
__launch_bounds__(256)
__global__ void k_scatter2(const int* __restrict__ ei, int E, int ET, int N,
                           const int* __restrict__ poff,
                           const unsigned short* __restrict__ rank,
                           int* __restrict__ csr_src){
    int i = blockIdx.x * 256 + threadIdx.x;
    if (i >= ET) return;
    int s, d;
    if (i < E){ s = ei[i]; d = ei[E + i]; } else { s = i - E; d = s; }
    int p = (i >> 8) & (NPART - 1);
    csr_src[poff[p * N + d] + (int)rank[i]] = s;
}

// ---------------- Fused: GEMM1 (blocks [0,nGemmBlk)) + hist_rank (rest) ----------------
// LDS = 24 KB (W staged in 8x16-row chunks) -> 6 blocks/CU for the latency-bound
// hist blocks. Hist path: 4 edges/thread (4 atomic returns in flight).

__launch_bounds__(256)
__global__ void k_gemm1_hist(const float* __restrict__ x, const float* __restrict__ W1,
                             const float* __restrict__ a_src, const float* __restrict__ a_dst,
                             _Float16* __restrict__ h1h, float* __restrict__ asrc1,
                             float* __restrict__ adst1, int N, int nGemmBlk,
                             const int* __restrict__ ei, int E, int ET,
                             int* __restrict__ degp, unsigned short* __restrict__ rank){
    __shared__ float Wl[16 * 128];    // 8 KB, one K-chunk of W, [k_local][col]
    __shared__ float xl[32 * 128];    // 16 KB
    int t = threadIdx.x;
    if ((int)blockIdx.x >= nGemmBlk){
        // ---- histogram + rank part: 1024 edges/block, 4 per thread ----
        int base = (blockIdx.x - nGemmBlk) * 1024 + t;
        #pragma unroll
        for (int j = 0; j < 4; j++){
            int i = base + j * 256;
            if (i < ET){
                int d = (i < E) ? ei[E + i] : (i - E);   // self loops appended
                int p = (i >> 8) & (NPART - 1);
                rank[i] = (unsigned short)atomicAdd(&degp[p * N + d], 1);
            }
        }
        return;
    }
    // ---- gemm1 part ----
    int cg = t & 31, ns = t >> 5;     // ns in 0..7
    int n0 = blockIdx.x * 32;
    for (int idx = t; idx < 1024; idx += 256){
        int row = idx >> 5, k4 = idx & 31;
        float4 v = {0.f, 0.f, 0.f, 0.f};
        if (n0 + row < N) v = *(const float4*)&x[(size_t)(n0 + row) * 128 + k4 * 4];
        *(float4*)&xl[row * 128 + k4 * 4] = v;
    }
    float4 acc0 = {0,0,0,0}, acc1 = {0,0,0,0}, acc2 = {0,0,0,0}, acc3 = {0,0,0,0};
    for (int c = 0; c < 8; c++){
        __syncthreads();               // xl ready (c=0) / Wl reads of prev chunk done
        for (int idx = t; idx < 512; idx += 256)
            *(float4*)&Wl[idx * 4] = *(const float4*)&W1[c * 16 * 128 + idx * 4];
        __syncthreads();
        #pragma unroll
        for (int k = 0; k < 16; k += 4){
            float4 xv0 = *(float4*)&xl[(ns     ) * 128 + c * 16 + k];
            float4 xv1 = *(float4*)&xl[(ns +  8) * 128 + c * 16 + k];
            float4 xv2 = *(float4*)&xl[(ns + 16) * 128 + c * 16 + k];
            float4 xv3 = *(float4*)&xl[(ns + 24) * 128 + c * 16 + k];
            #pragma unroll
            for (int kk = 0; kk < 4; kk++){
                float4 w = *(float4*)&Wl[(k + kk) * 128 + cg * 4];
                float x0 = ((float*)&xv0)[kk];
                float x1 = ((float*)&xv1)[kk];
                float x2v= ((float*)&xv2)[kk];
                float x3 = ((float*)&xv3)[kk];
                acc0.x = fmaf(x0, w.x, acc0.x); acc0.y = fmaf(x0, w.y, acc0.y);
                acc0.z = fmaf(x0, w.z, acc0.z); acc0.w = fmaf(x0, w.w, acc0.w);
                acc1.x = fmaf(x1, w.x, acc1.x); acc1.y = fmaf(x1, w.y, acc1.y);
                acc1.z = fmaf(x1, w.z, acc1.z); acc1.w = fmaf(x1, w.w, acc1.w);
                acc2.x = fmaf(x2v, w.x, acc2.x); acc2.y = fmaf(x2v, w.y, acc2.y);
                acc2.z = fmaf(x2v, w.z, acc2.z); acc2.w = fmaf(x2v, w.w, acc2.w);
                acc3.x = fmaf(x3, w.x, acc3.x); acc3.y = fmaf(x3, w.y, acc3.y);
                acc3.z = fmaf(x3, w.z, acc3.z); acc3.w = fmaf(x3, w.w, acc3.w);
            }
        }
    }
    float4 a4s = *(const float4*)&a_src[cg * 4];
    float4 a4d = *(const float4*)&a_dst[cg * 4];
    float4 accs[4] = {acc0, acc1, acc2, acc3};
    #pragma unroll
    for (int j = 0; j < 4; j++){
        int n = n0 + ns + 8 * j;
        if (n >= N) continue;
        float4 a = accs[j];
        half4 hv;
        hv.x = (_Float16)a.x; hv.y = (_Float16)a.y;
        hv.z = (_Float16)a.z; hv.w = (_Float16)a.w;
        *(half4*)&h1h[((size_t)n << 7) + (cg << 2)] = hv;
        float vs = a.x * a4s.x + a.y * a4s.y + a.z * a4s.z + a.w * a4s.w;
        float vd = a.x * a4d.x + a.y * a4d.y + a.z * a4d.z + a.w * a4d.w;
        #pragma unroll
        for (int m = 1; m <= 4; m <<= 1){
            vs += __shfl_xor(vs, m, 64);
            vd += __shfl_xor(vd, m, 64);
        }
        if ((cg & 7) == 0){
            int head = cg >> 3;
            asrc1[n * 4 + head] = vs;
            adst1[n * 4 + head] = vd;
        }
    }
}

// ---------------- Aggregation L1: wave/node, 4x16 lanes, unroll-2, v_pk_fma_f32 ----------

__launch_bounds__(256)
__global__ void k_agg1(const int* __restrict__ rowptr, const int* __restrict__ csr_src,
                       const float* __restrict__ asrc1, const float* __restrict__ adst1,
                       const _Float16* __restrict__ h1h,
                       const float* __restrict__ b1, float* __restrict__ x2){
    int t = threadIdx.x;
    int n = blockIdx.x * 4 + (t >> 6);
    int lane = t & 63, g = lane >> 4, l = lane & 15, head = l >> 2;
    int start = rowptr[n], end = rowptr[n + 1];
    float adn = adst1[(n << 2) + head];
    const char* hb = (const char*)h1h;
    const char* ab = (const char*)asrc1;
    int hoff = l << 4;
    int aoff = head << 2;
    floatx2 rA[4], rB[4];
    #pragma unroll
    for (int j = 0; j < 4; j++){ rA[j] = (floatx2)0.f; rB[j] = (floatx2)0.f; }
    float sA = 0.f, sB = 0.f;
    int i = start + g;
    for (; i + 4 < end; i += 8){
        int s0 = csr_src[i];
        int s1 = csr_src[i + 4];
        float e0 = *(const float*)(ab + (s0 << 4) + aoff) + adn;
        float e1 = *(const float*)(ab + (s1 << 4) + aoff) + adn;
        e0 = fmaxf(e0, NEG_SLOPE * e0);
        e1 = fmaxf(e1, NEG_SLOPE * e1);
        float w0 = __expf(e0);
        float w1 = __expf(e1);
        half8 h0 = *(const half8*)(hb + (s0 << 8) + hoff);
        half8 h1v = *(const half8*)(hb + (s1 << 8) + hoff);
        sA += w0; sB += w1;
        floatx2 w02 = {w0, w0}, w12 = {w1, w1};
        #pragma unroll
        for (int j = 0; j < 4; j++){
            floatx2 c0 = {(float)h0[2*j], (float)h0[2*j+1]};
            floatx2 c1 = {(float)h1v[2*j], (float)h1v[2*j+1]};
            rA[j] = w02 * c0 + rA[j];      // v_pk_fma_f32
            rB[j] = w12 * c1 + rB[j];
        }
    }
    if (i < end){
        int s0 = csr_src[i];
        float e0 = *(const float*)(ab + (s0 << 4) + aoff) + adn;
        e0 = fmaxf(e0, NEG_SLOPE * e0);
        float w0 = __expf(e0);
        half8 h0 = *(const half8*)(hb + (s0 << 8) + hoff);
        sA += w0;
        floatx2 w02 = {w0, w0};
        #pragma unroll
        for (int j = 0; j < 4; j++){
            floatx2 c0 = {(float)h0[2*j], (float)h0[2*j+1]};
            rA[j] = w02 * c0 + rA[j];
        }
    }
    float r[9];
    #pragma unroll
    for (int j = 0; j < 4; j++){
        floatx2 c = rA[j] + rB[j];
        r[2*j] = c.x; r[2*j+1] = c.y;
    }
    r[8] = sA + sB;
    #pragma unroll
    for (int m = 16; m <= 32; m <<= 1)
        #pragma unroll
        for (int j = 0; j < 9; j++) r[j] += __shfl_xor(r[j], m, 64);
    if (g == 0){
        float inv = 1.f / (r[8] + EPSV);
        float o[8];
        #pragma unroll
        for (int j = 0; j < 8; j++){
            float v = r[j] * inv + b1[l * 8 + j];
            o[j] = (v > 0.f) ? v : expm1f(v);   // ELU fused
        }
        float4 o0 = {o[0], o[1], o[2], o[3]};
        float4 o1 = {o[4], o[5], o[6], o[7]};
        *(float4*)&x2[((size_t)n << 7) + (l << 3)]     = o0;
        *(float4*)&x2[((size_t)n << 7) + (l << 3) + 4] = o1;
    }
}

// ---------------- GEMM2: h2 = x2 @ W2 (h2 stored fp16), 4-node blocking, k-unroll-4 ----

__launch_bounds__(256)
__global__ void k_gemm2(const float* __restrict__ x2, const float* __restrict__ W2,
                        const float* __restrict__ a_src, const float* __restrict__ a_dst,
                        _Float16* __restrict__ h2h, float* __restrict__ asrc2,
                        float* __restrict__ adst2, int N){
    __shared__ float Wl[128 * 32];    // 16 KB
    __shared__ float xl[128 * 128];   // 64 KB
    int t = threadIdx.x;
    int cg = t & 7, ns = t >> 3;      // ns in 0..31
    for (int idx = t; idx < 1024; idx += 256)
        *(float4*)&Wl[idx * 4] = *(const float4*)&W2[idx * 4];
    int n0 = blockIdx.x * 128;
    for (int idx = t; idx < 4096; idx += 256){
        int row = idx >> 5, k4 = idx & 31;
        float4 v = {0.f, 0.f, 0.f, 0.f};
        if (n0 + row < N) v = *(const float4*)&x2[(size_t)(n0 + row) * 128 + k4 * 4];
        *(float4*)&xl[row * 128 + k4 * 4] = v;
    }
    __syncthreads();
    float4 acc0 = {0,0,0,0}, acc1 = {0,0,0,0}, acc2 = {0,0,0,0}, acc3 = {0,0,0,0};
    #pragma unroll 2
    for (int k = 0; k < 128; k += 4){
        float4 xv0 = *(float4*)&xl[(ns      ) * 128 + k];
        float4 xv1 = *(float4*)&xl[(ns +  32) * 128 + k];
        float4 xv2 = *(float4*)&xl[(ns +  64) * 128 + k];
        float4 xv3 = *(float4*)&xl[(ns +  96) * 128 + k];
        #pragma unroll
        for (int kk = 0; kk < 4; kk++){
            float4 w = *(float4*)&Wl[(k + kk) * 32 + cg * 4];
            float x0 = ((float*)&xv0)[kk];
            float x1 = ((float*)&xv1)[kk];
            float x2v= ((float*)&xv2)[kk];
            float x3 = ((float*)&xv3)[kk];
            acc0.x = fmaf(x0, w.x, acc0.x); acc0.y = fmaf(x0, w.y, acc0.y);
            acc0.z = fmaf(x0, w.z, acc0.z); acc0.w = fmaf(x0, w.w, acc0.w);
            acc1.x = fmaf(x1, w.x, acc1.x); acc1.y = fmaf(x1, w.y, acc1.y);
            acc1.z = fmaf(x1, w.z, acc1.z); acc1.w = fmaf(x1, w.w, acc1.w);
            acc2.x = fmaf(x2v, w.x, acc2.x); acc2.y = fmaf(x2v, w.y, acc2.y);
            acc2.z = fmaf(x2v, w.z, acc2.z); acc2.w = fmaf(x2v, w.w, acc2.w);
            acc3.x = fmaf(x3, w.x, acc3.x); acc3.y = fmaf(x3, w.y, acc3.y);
            acc3.z = fmaf(x3, w.z, acc3.z); acc3.w = fmaf(x3, w.w, acc3.w);
        }
    }
    float4 a4s = *(const float4*)&a_src[cg * 4];
    float4 a4d = *(const float4*)&a_dst[cg * 4];
    float4 accs[4] = {acc0, acc1, acc2, acc3};
    #pragma unroll
    for (int j = 0; j < 4; j++){
        int n = n0 + ns + 32 * j;
        if (n >= N) continue;
        float4 a = accs[j];
        half4 hv;
        hv.x = (_Float16)a.x; hv.y = (_Float16)a.y;
        hv.z = (_Float16)a.z; hv.w = (_Float16)a.w;
        *(half4*)&h2h[((size_t)n << 5) + (cg << 2)] = hv;
        float vs = a.x * a4s.x + a.y * a4s.y + a.z * a4s.z + a.w * a4s.w;
        float vd = a.x * a4d.x + a.y * a4d.y + a.z * a4d.z + a.w * a4d.w;
        #pragma unroll
        for (int m = 1; m <= 4; m <<= 1){
            vs += __shfl_xor(vs, m, 64);
            vd += __shfl_xor(vd, m, 64);
        }
        if (cg == 0){ asrc2[n] = vs; adst2[n] = vd; }
    }
}

// ---------------- Aggregation L2: wave/node, 8x8 lanes, unroll-2, v_pk_fma_f32 ----------

__launch_bounds__(256)
__global__ void k_agg2(const int* __restrict__ rowptr, const int* __restrict__ csr_src,
                       const float* __restrict__ asrc2, const float* __restrict__ adst2,
                       const _Float16* __restrict__ h2h,
                       const float* __restrict__ b2, float* __restrict__ out){
    int t = threadIdx.x;
    int n = blockIdx.x * 4 + (t >> 6);
    int lane = t & 63, g = lane >> 3, l = lane & 7;
    int start = rowptr[n], end = rowptr[n + 1];
    float adn = adst2[n];
    const char* hb = (const char*)h2h;
    const char* ab = (const char*)asrc2;
    int hoff = l << 3;
    floatx2 aA[2], aB[2];
    aA[0] = (floatx2)0.f; aA[1] = (floatx2)0.f;
    aB[0] = (floatx2)0.f; aB[1] = (floatx2)0.f;
    float sA = 0.f, sB = 0.f;
    int i = start + g;
    for (; i + 8 < end; i += 16){
        int s0 = csr_src[i];
        int s1 = csr_src[i + 8];
        float e0 = *(const float*)(ab + (s0 << 2)) + adn;
        float e1 = *(const float*)(ab + (s1 << 2)) + adn;
        e0 = fmaxf(e0, NEG_SLOPE * e0);
        e1 = fmaxf(e1, NEG_SLOPE * e1);
        float w0 = __expf(e0);
        float w1 = __expf(e1);
        half4 h0 = *(const half4*)(hb + (s0 << 6) + hoff);
        half4 h1v = *(const half4*)(hb + (s1 << 6) + hoff);
        sA += w0; sB += w1;
        floatx2 w02 = {w0, w0}, w12 = {w1, w1};
        floatx2 c00 = {(float)h0.x, (float)h0.y}, c01 = {(float)h0.z, (float)h0.w};
        floatx2 c10 = {(float)h1v.x, (float)h1v.y}, c11 = {(float)h1v.z, (float)h1v.w};
        aA[0] = w02 * c00 + aA[0]; aA[1] = w02 * c01 + aA[1];
        aB[0] = w12 * c10 + aB[0]; aB[1] = w12 * c11 + aB[1];
    }
    if (i < end){
        int s0 = csr_src[i];
        float e0 = *(const float*)(ab + (s0 << 2)) + adn;
        e0 = fmaxf(e0, NEG_SLOPE * e0);
        float w0 = __expf(e0);
        half4 h0 = *(const half4*)(hb + (s0 << 6) + hoff);
        sA += w0;
        floatx2 w02 = {w0, w0};
        floatx2 c00 = {(float)h0.x, (float)h0.y}, c01 = {(float)h0.z, (float)h0.w};
        aA[0] = w02 * c00 + aA[0]; aA[1] = w02 * c01 + aA[1];
    }
    floatx2 m0 = aA[0] + aB[0], m1 = aA[1] + aB[1];
    float4 acc = {m0.x, m0.y, m1.x, m1.y};
    float ssum = sA + sB;
    #pragma unroll
    for (int m = 8; m <= 32; m <<= 1){
        acc.x += __shfl_xor(acc.x, m, 64);
        acc.y += __shfl_xor(acc.y, m, 64);
        acc.z += __shfl_xor(acc.z, m, 64);
        acc.w += __shfl_xor(acc.w, m, 64);
        ssum  += __shfl_xor(ssum,  m, 64);
    }
    if (g == 0){
        float inv = 1.f / (ssum + EPSV);
        const float4 b4 = *(const float4*)&b2[l * 4];
        float4 o;
        o.x = acc.x * inv + b4.x; o.y = acc.y * inv + b4.y;
        o.z = acc.z * inv + b4.z; o.w = acc.w * inv + b4.w;
        *(float4*)&out[((size_t)n << 5) + l * 4] = o;
    }
}

// ---------------- launch ----------------

extern "C" void kernel_launch(void* const* d_in, const int* in_sizes, int n_in,
                              void* d_out, int out_size, void* d_ws, size_t ws_size,
                              hipStream_t stream){
    const float* x      = (const float*)d_in[0];
    const int*   ei     = (const int*)  d_in[1];
    const float* W1     = (const float*)d_in[2];
    const float* a_src1 = (const float*)d_in[3];
    const float* a_dst1 = (const float*)d_in[4];
    const float* b1     = (const float*)d_in[5];
    const float* W2     = (const float*)d_in[6];
    const float* a_src2 = (const float*)d_in[7];
    const float* a_dst2 = (const float*)d_in[8];
    const float* b2     = (const float*)d_in[9];
    float* out = (float*)d_out;

    int N  = in_sizes[0] / 128;
    int E  = in_sizes[1] / 2;
    int ET = E + N;
    int nScanBlk = (N + 1023) / 1024;
    int G  = (ET + 255) / 256;
    int GH = (ET + 1023) / 1024;
    int nGemmBlk = (N + 31) / 32;

    char* ws = (char*)d_ws;
    size_t off = 0;
    auto alloc = [&](size_t bytes) -> char* {
        char* p = ws + off;
        off += (bytes + 255) & ~(size_t)255;
        return p;
    };
    int*            degp    = (int*)           alloc((size_t)NPART * N * 4);
    int*            rowptr  = (int*)           alloc((size_t)(N + 1) * 4);
    int*            bsum    = (int*)           alloc((size_t)nScanBlk * 4);
    unsigned short* rank    = (unsigned short*)alloc((size_t)ET * 2);
    int*            poff    = (int*)           alloc((size_t)NPART * N * 4);
    int*            csr_src = (int*)           alloc((size_t)ET * 4);
    _Float16*       h1h     = (_Float16*)      alloc((size_t)N * 128 * 2);
    float*          x2      = (float*)         alloc((size_t)N * 128 * 4);
    float*          asrc1   = (float*)         alloc((size_t)N * 4 * 4);
    float*          adst1   = (float*)         alloc((size_t)N * 4 * 4);
    _Float16*       h2h     = (_Float16*)      alloc((size_t)N * 32 * 2);
    float*          asrc2   = (float*)         alloc((size_t)N * 4);
    float*          adst2   = (float*)         alloc((size_t)N * 4);

    hipMemsetAsync(degp, 0, (size_t)NPART * N * 4, stream);
    hipLaunchKernelGGL(k_gemm1_hist, dim3(nGemmBlk + GH), dim3(256), 0, stream,
                       x, W1, a_src1, a_dst1, h1h, asrc1, adst1, N, nGemmBlk,
                       ei, E, ET, degp, rank);
    hipLaunchKernelGGL(k_scan_blk,  dim3(nScanBlk), dim3(256), 0, stream, degp, N, rowptr, bsum);
    hipLaunchKernelGGL(k_finalize,  dim3((N + 255) / 256), dim3(256), 0, stream, bsum, degp, N, ET, rowptr, poff);
    hipLaunchKernelGGL(k_scatter2,  dim3(G), dim3(256), 0, stream, ei, E, ET, N, poff, rank, csr_src);
    hipLaunchKernelGGL(k_agg1,      dim3(N / 4), dim3(256), 0, stream, rowptr, csr_src, asrc1, adst1, h1h, b1, x2);
    hipLaunchKernelGGL(k_gemm2,     dim3((N + 127) / 128), dim3(256), 0, stream, x2, W2, a_src2, a_dst2, h2h, asrc2, adst2, N);
    hipLaunchKernelGGL(k_agg2,      dim3(N / 4), dim3(256), 0, stream, rowptr, csr_src, asrc2, adst2, h2h, b2, out);
}

// Round 14
// 305.130 us; speedup vs baseline: 1.0368x; 1.0368x over previous
//
#include <hip/hip_runtime.h>
#include <math.h>

#define NEG_SLOPE 0.2f
#define EPSV 1e-16f
#define NPART 4

typedef _Float16 half4 __attribute__((ext_vector_type(4)));
typedef _Float16 half8 __attribute__((ext_vector_type(8)));
typedef float floatx2 __attribute__((ext_vector_type(2)));

// ---------------- CSR build ----------------

// block scan over 1024-node chunks; deg computed inline from degp; bsum = raw chunk sum
__global__ void k_scan_blk(const int* __restrict__ degp, int N,
                           int* __restrict__ rowptr, int* __restrict__ bsum){
    int b = blockIdx.x, t = threadIdx.x;
    int base = b * 1024 + t * 4;
    int v[4];
    #pragma unroll
    for (int j = 0; j < 4; j++){
        int n = base + j, s = 0;
        if (n < N){
            #pragma unroll
            for (int p = 0; p < NPART; p++) s += degp[p * N + n];
        }
        v[j] = s;
    }
    int s = v[0] + v[1] + v[2] + v[3];
    int lane = t & 63, wid = t >> 6;
    int x = s;
    #pragma unroll
    for (int off = 1; off < 64; off <<= 1){
        int y = __shfl_up(x, off, 64);
        if (lane >= off) x += y;
    }
    __shared__ int ws[4];
    if (lane == 63) ws[wid] = x;
    __syncthreads();
    int woff = 0;
    for (int w = 0; w < wid; w++) woff += ws[w];
    int run = woff + x - s;
    #pragma unroll
    for (int j = 0; j < 4; j++){
        if (base + j < N) rowptr[base + j] = run;
        run += v[j];
    }
    if (t == 255) bsum[b] = woff + x;
}

// rowptr += prefix(bsum); poff[p][n] = rowptr[n] + prefix_p(degp[.][n])
__global__ void k_finalize(const int* __restrict__ bsum, const int* __restrict__ degp,
                           int N, int ET,
                           int* __restrict__ rowptr, int* __restrict__ poff){
    int b = blockIdx.x, t = threadIdx.x;
    int n = b * 256 + t;
    int chunk = (b * 256) >> 10;           // wave-uniform
    int off = 0;
    for (int c = 0; c < chunk; c++) off += bsum[c];
    if (n < N){
        int r = rowptr[n] + off;
        rowptr[n] = r;
        int run = r;
        #pragma unroll
        for (int p = 0; p < NPART; p++){
            poff[p * N + n] = run;
            run += degp[p * N + n];
        }
    }
    if (n == 0) rowptr[N] = ET;
}

// atomic-free scatter (src only; dst implicit via rowptr ranges); partition = (i>>8)&3
__launch_bounds__(256)
__global__ void k_scatter2(const int* __restrict__ ei, int E, int ET, int N,
                           const int* __restrict__ poff,
                           const unsigned short* __restrict__ rank,
                           int* __restrict__ csr_src){
    int i = blockIdx.x * 256 + threadIdx.x;
    if (i >= ET) return;
    int s, d;
    if (i < E){ s = ei[i]; d = ei[E + i]; } else { s = i - E; d = s; }
    int p = (i >> 8) & (NPART - 1);
    csr_src[poff[p * N + d] + (int)rank[i]] = s;
}

// ---------------- Fused: GEMM1 (blocks [0,nGemmBlk)) + hist_rank (rest) ----------------
// LDS = 24 KB -> 6 blocks/CU. Hist path: 4 edges/thread (4 atomic returns in flight).

__launch_bounds__(256)
__global__ void k_gemm1_hist(const float* __restrict__ x, const float* __restrict__ W1,
                             const float* __restrict__ a_src, const float* __restrict__ a_dst,
                             _Float16* __restrict__ h1h, float* __restrict__ asrc1,
                             float* __restrict__ adst1, int N, int nGemmBlk,
                             const int* __restrict__ ei, int E, int ET,
                             int* __restrict__ degp, unsigned short* __restrict__ rank){
    __shared__ float Wl[16 * 128];    // 8 KB, one K-chunk of W, [k_local][col]
    __shared__ float xl[32 * 128];    // 16 KB
    int t = threadIdx.x;
    if ((int)blockIdx.x >= nGemmBlk){
        // ---- histogram + rank part: 1024 edges/block, 4 per thread ----
        int base = (blockIdx.x - nGemmBlk) * 1024 + t;
        #pragma unroll
        for (int j = 0; j < 4; j++){
            int i = base + j * 256;
            if (i < ET){
                int d = (i < E) ? ei[E + i] : (i - E);   // self loops appended
                int p = (i >> 8) & (NPART - 1);
                rank[i] = (unsigned short)atomicAdd(&degp[p * N + d], 1);
            }
        }
        return;
    }
    // ---- gemm1 part ----
    int cg = t & 31, ns = t >> 5;     // ns in 0..7
    int n0 = blockIdx.x * 32;
    for (int idx = t; idx < 1024; idx += 256){
        int row = idx >> 5, k4 = idx & 31;
        float4 v = {0.f, 0.f, 0.f, 0.f};
        if (n0 + row < N) v = *(const float4*)&x[(size_t)(n0 + row) * 128 + k4 * 4];
        *(float4*)&xl[row * 128 + k4 * 4] = v;
    }
    float4 acc0 = {0,0,0,0}, acc1 = {0,0,0,0}, acc2 = {0,0,0,0}, acc3 = {0,0,0,0};
    for (int c = 0; c < 8; c++){
        __syncthreads();               // xl ready (c=0) / Wl reads of prev chunk done
        for (int idx = t; idx < 512; idx += 256)
            *(float4*)&Wl[idx * 4] = *(const float4*)&W1[c * 16 * 128 + idx * 4];
        __syncthreads();
        #pragma unroll
        for (int k = 0; k < 16; k += 4){
            float4 xv0 = *(float4*)&xl[(ns     ) * 128 + c * 16 + k];
            float4 xv1 = *(float4*)&xl[(ns +  8) * 128 + c * 16 + k];
            float4 xv2 = *(float4*)&xl[(ns + 16) * 128 + c * 16 + k];
            float4 xv3 = *(float4*)&xl[(ns + 24) * 128 + c * 16 + k];
            #pragma unroll
            for (int kk = 0; kk < 4; kk++){
                float4 w = *(float4*)&Wl[(k + kk) * 128 + cg * 4];
                float x0 = ((float*)&xv0)[kk];
                float x1 = ((float*)&xv1)[kk];
                float x2v= ((float*)&xv2)[kk];
                float x3 = ((float*)&xv3)[kk];
                acc0.x = fmaf(x0, w.x, acc0.x); acc0.y = fmaf(x0, w.y, acc0.y);
                acc0.z = fmaf(x0, w.z, acc0.z); acc0.w = fmaf(x0, w.w, acc0.w);
                acc1.x = fmaf(x1, w.x, acc1.x); acc1.y = fmaf(x1, w.y, acc1.y);
                acc1.z = fmaf(x1, w.z, acc1.z); acc1.w = fmaf(x1, w.w, acc1.w);
                acc2.x = fmaf(x2v, w.x, acc2.x); acc2.y = fmaf(x2v, w.y, acc2.y);
                acc2.z = fmaf(x2v, w.z, acc2.z); acc2.w = fmaf(x2v, w.w, acc2.w);
                acc3.x = fmaf(x3, w.x, acc3.x); acc3.y = fmaf(x3, w.y, acc3.y);
                acc3.z = fmaf(x3, w.z, acc3.z); acc3.w = fmaf(x3, w.w, acc3.w);
            }
        }
    }
    float4 a4s = *(const float4*)&a_src[cg * 4];
    float4 a4d = *(const float4*)&a_dst[cg * 4];
    float4 accs[4] = {acc0, acc1, acc2, acc3};
    #pragma unroll
    for (int j = 0; j < 4; j++){
        int n = n0 + ns + 8 * j;
        if (n >= N) continue;
        float4 a = accs[j];
        half4 hv;
        hv.x = (_Float16)a.x; hv.y = (_Float16)a.y;
        hv.z = (_Float16)a.z; hv.w = (_Float16)a.w;
        *(half4*)&h1h[((size_t)n << 7) + (cg << 2)] = hv;
        float vs = a.x * a4s.x + a.y * a4s.y + a.z * a4s.z + a.w * a4s.w;
        float vd = a.x * a4d.x + a.y * a4d.y + a.z * a4d.z + a.w * a4d.w;
        #pragma unroll
        for (int m = 1; m <= 4; m <<= 1){
            vs += __shfl_xor(vs, m, 64);
            vd += __shfl_xor(vd, m, 64);
        }
        if ((cg & 7) == 0){
            int head = cg >> 3;
            asrc1[n * 4 + head] = vs;
            adst1[n * 4 + head] = vd;
        }
    }
}

// ---------------- Aggregation L1: wave/node, 4x16 lanes, unroll-2, v_pk_fma_f32 ----------

__launch_bounds__(256)
__global__ void k_agg1(const int* __restrict__ rowptr, const int* __restrict__ csr_src,
                       const float* __restrict__ asrc1, const float* __restrict__ adst1,
                       const _Float16* __restrict__ h1h,
                       const float* __restrict__ b1, float* __restrict__ x2){
    int t = threadIdx.x;
    int n = blockIdx.x * 4 + (t >> 6);
    int lane = t & 63, g = lane >> 4, l = lane & 15, head = l >> 2;
    int start = rowptr[n], end = rowptr[n + 1];
    float adn = adst1[(n << 2) + head];
    const char* hb = (const char*)h1h;
    const char* ab = (const char*)asrc1;
    int hoff = l << 4;
    int aoff = head << 2;
    floatx2 rA[4], rB[4];
    #pragma unroll
    for (int j = 0; j < 4; j++){ rA[j] = (floatx2)0.f; rB[j] = (floatx2)0.f; }
    float sA = 0.f, sB = 0.f;
    int i = start + g;
    for (; i + 4 < end; i += 8){
        int s0 = csr_src[i];
        int s1 = csr_src[i + 4];
        float e0 = *(const float*)(ab + (s0 << 4) + aoff) + adn;
        float e1 = *(const float*)(ab + (s1 << 4) + aoff) + adn;
        e0 = fmaxf(e0, NEG_SLOPE * e0);
        e1 = fmaxf(e1, NEG_SLOPE * e1);
        float w0 = __expf(e0);
        float w1 = __expf(e1);
        half8 h0 = *(const half8*)(hb + (s0 << 8) + hoff);
        half8 h1v = *(const half8*)(hb + (s1 << 8) + hoff);
        sA += w0; sB += w1;
        floatx2 w02 = {w0, w0}, w12 = {w1, w1};
        #pragma unroll
        for (int j = 0; j < 4; j++){
            floatx2 c0 = {(float)h0[2*j], (float)h0[2*j+1]};
            floatx2 c1 = {(float)h1v[2*j], (float)h1v[2*j+1]};
            rA[j] = w02 * c0 + rA[j];      // v_pk_fma_f32
            rB[j] = w12 * c1 + rB[j];
        }
    }
    if (i < end){
        int s0 = csr_src[i];
        float e0 = *(const float*)(ab + (s0 << 4) + aoff) + adn;
        e0 = fmaxf(e0, NEG_SLOPE * e0);
        float w0 = __expf(e0);
        half8 h0 = *(const half8*)(hb + (s0 << 8) + hoff);
        sA += w0;
        floatx2 w02 = {w0, w0};
        #pragma unroll
        for (int j = 0; j < 4; j++){
            floatx2 c0 = {(float)h0[2*j], (float)h0[2*j+1]};
            rA[j] = w02 * c0 + rA[j];
        }
    }
    float r[9];
    #pragma unroll
    for (int j = 0; j < 4; j++){
        floatx2 c = rA[j] + rB[j];
        r[2*j] = c.x; r[2*j+1] = c.y;
    }
    r[8] = sA + sB;
    #pragma unroll
    for (int m = 16; m <= 32; m <<= 1)
        #pragma unroll
        for (int j = 0; j < 9; j++) r[j] += __shfl_xor(r[j], m, 64);
    if (g == 0){
        float inv = 1.f / (r[8] + EPSV);
        float o[8];
        #pragma unroll
        for (int j = 0; j < 8; j++){
            float v = r[j] * inv + b1[l * 8 + j];
            o[j] = (v > 0.f) ? v : expm1f(v);   // ELU fused
        }
        float4 o0 = {o[0], o[1], o[2], o[3]};
        float4 o1 = {o[4], o[5], o[6], o[7]};
        *(float4*)&x2[((size_t)n << 7) + (l << 3)]     = o0;
        *(float4*)&x2[((size_t)n << 7) + (l << 3) + 4] = o1;
    }
}

// ---------------- GEMM2: 64-node tile, 48 KB LDS (3 blocks/CU), 2-node blocking ----------

__launch_bounds__(256)
__global__ void k_gemm2(const float* __restrict__ x2, const float* __restrict__ W2,
                        const float* __restrict__ a_src, const float* __restrict__ a_dst,
                        _Float16* __restrict__ h2h, float* __restrict__ asrc2,
                        float* __restrict__ adst2, int N){
    __shared__ float Wl[128 * 32];    // 16 KB
    __shared__ float xl[64 * 128];    // 32 KB
    int t = threadIdx.x;
    int cg = t & 7, ns = t >> 3;      // ns in 0..31
    for (int idx = t; idx < 1024; idx += 256)
        *(float4*)&Wl[idx * 4] = *(const float4*)&W2[idx * 4];
    int n0 = blockIdx.x * 64;
    for (int idx = t; idx < 2048; idx += 256){
        int row = idx >> 5, k4 = idx & 31;
        float4 v = {0.f, 0.f, 0.f, 0.f};
        if (n0 + row < N) v = *(const float4*)&x2[(size_t)(n0 + row) * 128 + k4 * 4];
        *(float4*)&xl[row * 128 + k4 * 4] = v;
    }
    __syncthreads();
    float4 acc0 = {0,0,0,0}, acc1 = {0,0,0,0};
    #pragma unroll 2
    for (int k = 0; k < 128; k += 4){
        float4 xv0 = *(float4*)&xl[(ns      ) * 128 + k];
        float4 xv1 = *(float4*)&xl[(ns + 32) * 128 + k];
        #pragma unroll
        for (int kk = 0; kk < 4; kk++){
            float4 w = *(float4*)&Wl[(k + kk) * 32 + cg * 4];
            float x0 = ((float*)&xv0)[kk];
            float x1 = ((float*)&xv1)[kk];
            acc0.x = fmaf(x0, w.x, acc0.x); acc0.y = fmaf(x0, w.y, acc0.y);
            acc0.z = fmaf(x0, w.z, acc0.z); acc0.w = fmaf(x0, w.w, acc0.w);
            acc1.x = fmaf(x1, w.x, acc1.x); acc1.y = fmaf(x1, w.y, acc1.y);
            acc1.z = fmaf(x1, w.z, acc1.z); acc1.w = fmaf(x1, w.w, acc1.w);
        }
    }
    float4 a4s = *(const float4*)&a_src[cg * 4];
    float4 a4d = *(const float4*)&a_dst[cg * 4];
    float4 accs[2] = {acc0, acc1};
    #pragma unroll
    for (int j = 0; j < 2; j++){
        int n = n0 + ns + 32 * j;
        if (n >= N) continue;
        float4 a = accs[j];
        half4 hv;
        hv.x = (_Float16)a.x; hv.y = (_Float16)a.y;
        hv.z = (_Float16)a.z; hv.w = (_Float16)a.w;
        *(half4*)&h2h[((size_t)n << 5) + (cg << 2)] = hv;
        float vs = a.x * a4s.x + a.y * a4s.y + a.z * a4s.z + a.w * a4s.w;
        float vd = a.x * a4d.x + a.y * a4d.y + a.z * a4d.z + a.w * a4d.w;
        #pragma unroll
        for (int m = 1; m <= 4; m <<= 1){
            vs += __shfl_xor(vs, m, 64);
            vd += __shfl_xor(vd, m, 64);
        }
        if (cg == 0){ asrc2[n] = vs; adst2[n] = vd; }
    }
}

// ---------------- Aggregation L2: 2 nodes/wave, 4 groups x 8 lanes, unroll-2 ----------

__launch_bounds__(256)
__global__ void k_agg2(const int* __restrict__ rowptr, const int* __restrict__ csr_src,
                       const float* __restrict__ asrc2, const float* __restrict__ adst2,
                       const _Float16* __restrict__ h2h,
                       const float* __restrict__ b2, float* __restrict__ out){
    int t = threadIdx.x;
    int n = blockIdx.x * 8 + (t >> 5);
    int l5 = t & 31, g = l5 >> 3, l = l5 & 7;
    int start = rowptr[n], end = rowptr[n + 1];
    float adn = adst2[n];
    const char* hb = (const char*)h2h;
    const char* ab = (const char*)asrc2;
    int hoff = l << 3;
    floatx2 aA[2], aB[2];
    aA[0] = (floatx2)0.f; aA[1] = (floatx2)0.f;
    aB[0] = (floatx2)0.f; aB[1] = (floatx2)0.f;
    float sA = 0.f, sB = 0.f;
    int i = start + g;
    for (; i + 4 < end; i += 8){
        int s0 = csr_src[i];
        int s1 = csr_src[i + 4];
        float e0 = *(const float*)(ab + (s0 << 2)) + adn;
        float e1 = *(const float*)(ab + (s1 << 2)) + adn;
        e0 = fmaxf(e0, NEG_SLOPE * e0);
        e1 = fmaxf(e1, NEG_SLOPE * e1);
        float w0 = __expf(e0);
        float w1 = __expf(e1);
        half4 h0 = *(const half4*)(hb + (s0 << 6) + hoff);
        half4 h1v = *(const half4*)(hb + (s1 << 6) + hoff);
        sA += w0; sB += w1;
        floatx2 w02 = {w0, w0}, w12 = {w1, w1};
        floatx2 c00 = {(float)h0.x, (float)h0.y}, c01 = {(float)h0.z, (float)h0.w};
        floatx2 c10 = {(float)h1v.x, (float)h1v.y}, c11 = {(float)h1v.z, (float)h1v.w};
        aA[0] = w02 * c00 + aA[0]; aA[1] = w02 * c01 + aA[1];
        aB[0] = w12 * c10 + aB[0]; aB[1] = w12 * c11 + aB[1];
    }
    if (i < end){
        int s0 = csr_src[i];
        float e0 = *(const float*)(ab + (s0 << 2)) + adn;
        e0 = fmaxf(e0, NEG_SLOPE * e0);
        float w0 = __expf(e0);
        half4 h0 = *(const half4*)(hb + (s0 << 6) + hoff);
        sA += w0;
        floatx2 w02 = {w0, w0};
        floatx2 c00 = {(float)h0.x, (float)h0.y}, c01 = {(float)h0.z, (float)h0.w};
        aA[0] = w02 * c00 + aA[0]; aA[1] = w02 * c01 + aA[1];
    }
    floatx2 m0 = aA[0] + aB[0], m1 = aA[1] + aB[1];
    float4 acc = {m0.x, m0.y, m1.x, m1.y};
    float ssum = sA + sB;
    #pragma unroll
    for (int m = 8; m <= 16; m <<= 1){
        acc.x += __shfl_xor(acc.x, m, 64);
        acc.y += __shfl_xor(acc.y, m, 64);
        acc.z += __shfl_xor(acc.z, m, 64);
        acc.w += __shfl_xor(acc.w, m, 64);
        ssum  += __shfl_xor(ssum,  m, 64);
    }
    if (g == 0){
        float inv = 1.f / (ssum + EPSV);
        const float4 b4 = *(const float4*)&b2[l * 4];
        float4 o;
        o.x = acc.x * inv + b4.x; o.y = acc.y * inv + b4.y;
        o.z = acc.z * inv + b4.z; o.w = acc.w * inv + b4.w;
        *(float4*)&out[((size_t)n << 5) + l * 4] = o;
    }
}

// ---------------- launch ----------------

extern "C" void kernel_launch(void* const* d_in, const int* in_sizes, int n_in,
                              void* d_out, int out_size, void* d_ws, size_t ws_size,
                              hipStream_t stream){
    const float* x      = (const float*)d_in[0];
    const int*   ei     = (const int*)  d_in[1];
    const float* W1     = (const float*)d_in[2];
    const float* a_src1 = (const float*)d_in[3];
    const float* a_dst1 = (const float*)d_in[4];
    const float* b1     = (const float*)d_in[5];
    const float* W2     = (const float*)d_in[6];
    const float* a_src2 = (const float*)d_in[7];
    const float* a_dst2 = (const float*)d_in[8];
    const float* b2     = (const float*)d_in[9];
    float* out = (float*)d_out;

    int N  = in_sizes[0] / 128;
    int E  = in_sizes[1] / 2;
    int ET = E + N;
    int nScanBlk = (N + 1023) / 1024;
    int G  = (ET + 255) / 256;
    int GH = (ET + 1023) / 1024;
    int nGemmBlk = (N + 31) / 32;

    char* ws = (char*)d_ws;
    size_t off = 0;
    auto alloc = [&](size_t bytes) -> char* {
        char* p = ws + off;
        off += (bytes + 255) & ~(size_t)255;
        return p;
    };
    int*            degp    = (int*)           alloc((size_t)NPART * N * 4);
    int*            rowptr  = (int*)           alloc((size_t)(N + 1) * 4);
    int*            bsum    = (int*)           alloc((size_t)nScanBlk * 4);
    unsigned short* rank    = (unsigned short*)alloc((size_t)ET * 2);
    int*            poff    = (int*)           alloc((size_t)NPART * N * 4);
    int*            csr_src = (int*)           alloc((size_t)ET * 4);
    _Float16*       h1h     = (_Float16*)      alloc((size_t)N * 128 * 2);
    float*          x2      = (float*)         alloc((size_t)N * 128 * 4);
    float*          asrc1   = (float*)         alloc((size_t)N * 4 * 4);
    float*          adst1   = (float*)         alloc((size_t)N * 4 * 4);
    _Float16*       h2h     = (_Float16*)      alloc((size_t)N * 32 * 2);
    float*          asrc2   = (float*)         alloc((size_t)N * 4);
    float*          adst2   = (float*)         alloc((size_t)N * 4);

    hipMemsetAsync(degp, 0, (size_t)NPART * N * 4, stream);
    hipLaunchKernelGGL(k_gemm1_hist, dim3(nGemmBlk + GH), dim3(256), 0, stream,
                       x, W1, a_src1, a_dst1, h1h, asrc1, adst1, N, nGemmBlk,
                       ei, E, ET, degp, rank);
    hipLaunchKernelGGL(k_scan_blk,  dim3(nScanBlk), dim3(256), 0, stream, degp, N, rowptr, bsum);
    hipLaunchKernelGGL(k_finalize,  dim3((N + 255) / 256), dim3(256), 0, stream, bsum, degp, N, ET, rowptr, poff);
    hipLaunchKernelGGL(k_scatter2,  dim3(G), dim3(256), 0, stream, ei, E, ET, N, poff, rank, csr_src);
    hipLaunchKernelGGL(k_agg1,      dim3(N / 4), dim3(256), 0, stream, rowptr, csr_src, asrc1, adst1, h1h, b1, x2);
    hipLaunchKernelGGL(k_gemm2,     dim3((N + 63) / 64), dim3(256), 0, stream, x2, W2, a_src2, a_dst2, h2h, asrc2, adst2, N);
    hipLaunchKernelGGL(k_agg2,      dim3(N / 8), dim3(256), 0, stream, rowptr, csr_src, asrc2, adst2, h2h, b2, out);
}